// Round 2
// baseline (4465.087 us; speedup 1.0000x reference)
//
#include <hip/hip_runtime.h>
#include <stdint.h>

typedef unsigned long long u64;
typedef unsigned int u32;

#define NTOT 270072
#define TOPK 6000
#define POSTK 1000
#define NW 94              // ceil(6000/64)
#define COMPCAP 8192
#define INVALID_KEY 0xBF800000u

// ---------------------------------------------------------------------------
// Weight transform: OIHW [co][ci][3][3] -> [ci][kh][kw][co] for coalesced LDS
// staging in the conv kernel.
// ---------------------------------------------------------------------------
__global__ __launch_bounds__(256) void wtrans_k(const float* __restrict__ w3,
                                                float* __restrict__ wt) {
    int i = blockIdx.x * 256 + threadIdx.x;
    if (i < 589824) {
        int co = i & 255;
        int t = i >> 8;
        int kw = t % 3, kh = (t / 3) % 3, ci = t / 9;
        wt[i] = w3[co * 2304 + ci * 9 + kh * 3 + kw];
    }
}

// ---------------------------------------------------------------------------
// Fused: 3x3 conv (256->256) + bias + relu + 1x1 cls/bbox convs + softmax +
// anchor decode + clip + min-size filter -> per-anchor sort key + box.
// Block: 256 threads, one (level,b,h,32-wide tile). Per thread: 4px x 8co.
// __launch_bounds__(256,4): LDS (39.4KB) caps us at 4 blocks/CU = 4 waves/SIMD
// anyway; allow 128 VGPRs so the 32-reg accumulator tile isn't spilled.
// ---------------------------------------------------------------------------
__global__ __launch_bounds__(256, 4) void conv_fused_k(
    const float* __restrict__ f0, const float* __restrict__ f1,
    const float* __restrict__ f2, const float* __restrict__ f3,
    const float* __restrict__ f4,
    const float* __restrict__ wt, const float* __restrict__ convb,
    const float* __restrict__ clsw, const float* __restrict__ clsb,
    const float* __restrict__ bbw, const float* __restrict__ bbb,
    const float* __restrict__ im_info,
    u32* __restrict__ keys, float4* __restrict__ boxes)
{
    const int   Ht[5]      = {12, 24, 48, 96, 192};
    const int   Wt[5]      = {22, 44, 88, 176, 352};
    const int   tstart[5]  = {0, 12, 60, 204, 780};
    const int   tilesX[5]  = {1, 2, 3, 6, 11};
    const int   baseA[5]   = {0, 792, 3960, 16632, 67320};
    const float scaleA[5]  = {32.f, 16.f, 8.f, 4.f, 2.f};
    const float strideA[5] = {64.f, 32.f, 16.f, 8.f, 4.f};

    __shared__ __align__(16) float wlds[9216];  // 4ci x 9 x 256co (also reused as t[256][33])
    __shared__ __align__(16) float xs[576];     // 4ci x 3 x 34 staging (reused as arr18[32][18])

    int bid = blockIdx.x;
    int lev = (bid < 12) ? 0 : (bid < 60) ? 1 : (bid < 204) ? 2 : (bid < 780) ? 3 : 4;
    int tl_ = bid - tstart[lev];
    int H = Ht[lev], W = Wt[lev];
    int h = tl_ / tilesX[lev];
    int w0 = (tl_ - h * tilesX[lev]) * 32;
    int b = blockIdx.y;
    const float* x = (lev == 0) ? f0 : (lev == 1) ? f1 : (lev == 2) ? f2 : (lev == 3) ? f3 : f4;

    int tid = threadIdx.x;
    int pxg = tid & 7;        // pixel group: px = pxg*4 + p
    int cog = tid >> 3;       // co group:    co = cog*8 + c

    float acc[4][8];
#pragma unroll
    for (int p = 0; p < 4; ++p)
#pragma unroll
        for (int c = 0; c < 8; ++c) acc[p][c] = 0.f;

    const float* xb = x + (size_t)b * 256 * H * W;

    for (int ci0 = 0; ci0 < 256; ci0 += 4) {
        __syncthreads();
        // stage x halo tile: [4ci][3 rows][34 cols]
        for (int i = tid; i < 408; i += 256) {
            int cc = i / 102;
            int rem = i - cc * 102;
            int r = rem / 34;
            int col = rem - r * 34;
            int gh = h - 1 + r, gw = w0 - 1 + col;
            float v = 0.f;
            if (gh >= 0 && gh < H && gw >= 0 && gw < W)
                v = xb[((ci0 + cc) * H + gh) * W + gw];
            xs[i] = v;
        }
        // stage weights: 9216 floats = 2304 float4, coalesced
        const float4* wsrc = (const float4*)(wt + (size_t)ci0 * 2304);
        float4* wdst = (float4*)wlds;
#pragma unroll
        for (int i = 0; i < 9; ++i) wdst[tid + i * 256] = wsrc[tid + i * 256];
        __syncthreads();

#pragma unroll
        for (int cc = 0; cc < 4; ++cc)
#pragma unroll
            for (int kh = 0; kh < 3; ++kh) {
                const float* xr = &xs[(cc * 3 + kh) * 34 + pxg * 4];
                float xv[6];
#pragma unroll
                for (int q = 0; q < 6; ++q) xv[q] = xr[q];
                const float* wr = &wlds[(cc * 3 + kh) * 3 * 256 + cog * 8];
#pragma unroll
                for (int kw = 0; kw < 3; ++kw) {
                    float4 wa = *(const float4*)(wr + kw * 256);
                    float4 wb = *(const float4*)(wr + kw * 256 + 4);
                    float wv[8] = {wa.x, wa.y, wa.z, wa.w, wb.x, wb.y, wb.z, wb.w};
#pragma unroll
                    for (int p = 0; p < 4; ++p)
#pragma unroll
                        for (int c = 0; c < 8; ++c)
                            acc[p][c] = fmaf(xv[p + kw], wv[c], acc[p][c]);
                }
            }
    }

    // epilogue: t = relu(acc + bias) into LDS [co][33]
    __syncthreads();
    float bco[8];
#pragma unroll
    for (int c = 0; c < 8; ++c) bco[c] = convb[cog * 8 + c];
    float* tl = wlds;  // 256*33 = 8448 floats <= 9216
#pragma unroll
    for (int p = 0; p < 4; ++p)
#pragma unroll
        for (int c = 0; c < 8; ++c)
            tl[(cog * 8 + c) * 33 + pxg * 4 + p] = fmaxf(acc[p][c] + bco[c], 0.f);
    __syncthreads();

    // 1x1 convs: 32px x 18ch
    float* arr18 = xs;  // 576 floats
    for (int oi = tid; oi < 576; oi += 256) {
        int px = oi / 18, ch = oi - px * 18;
        const float* wp = (ch < 6) ? (clsw + ch * 256) : (bbw + (ch - 6) * 256);
        float s = (ch < 6) ? clsb[ch] : bbb[ch - 6];
        for (int co = 0; co < 256; co += 4) {
            float4 wv = *(const float4*)(wp + co);
            s = fmaf(tl[(co + 0) * 33 + px], wv.x, s);
            s = fmaf(tl[(co + 1) * 33 + px], wv.y, s);
            s = fmaf(tl[(co + 2) * 33 + px], wv.z, s);
            s = fmaf(tl[(co + 3) * 33 + px], wv.w, s);
        }
        arr18[oi] = s;
    }
    __syncthreads();

    // softmax + decode + clip + filter + key for 32px x 3 anchors
    if (tid < 96) {
        int px = tid / 3, a = tid - px * 3;
        int w = w0 + px;
        if (w < W) {
            const float* e = &arr18[px * 18];
            float l0 = e[a * 2], l1 = e[a * 2 + 1];
            float m = fmaxf(l0, l1);
            float e0 = expf(l0 - m), e1 = expf(l1 - m);
            float score = e1 / (e0 + e1);
            float d0 = e[6 + a * 4 + 0], d1 = e[6 + a * 4 + 1];
            float d2 = e[6 + a * 4 + 2], d3 = e[6 + a * 4 + 3];
            const float wsA[3] = {16.f, 11.f, 9.f};
            const float hsA[3] = {16.f, 22.f, 27.f};
            float aw = wsA[a] * scaleA[lev], ah = hsA[a] * scaleA[lev];
            float ax = 8.f + w * strideA[lev];
            float ay = 8.f + h * strideA[lev];
            float pcx = ax + d0 * aw, pcy = ay + d1 * ah;
            float pw = aw * expf(d2), ph = ah * expf(d3);
            float x1 = pcx - 0.5f * pw, y1 = pcy - 0.5f * ph;
            float x2 = pcx + 0.5f * pw, y2 = pcy + 0.5f * ph;
            float him = im_info[b * 6 + 0], wim = im_info[b * 6 + 1], sim = im_info[b * 6 + 2];
            x1 = fminf(fmaxf(x1, 0.f), wim - 1.f);
            y1 = fminf(fmaxf(y1, 0.f), him - 1.f);
            x2 = fminf(fmaxf(x2, 0.f), wim - 1.f);
            y2 = fminf(fmaxf(y2, 0.f), him - 1.f);
            float thr = 2.f * sim;
            if (!((x2 - x1 + 1.f >= thr) && (y2 - y1 + 1.f >= thr))) score = -1.f;
            u32 u = __float_as_uint(score);
            u32 okey = u ^ ((u >> 31) ? 0xFFFFFFFFu : 0x80000000u);
            u32 k = ~okey;  // ascending sort => descending score
            int gi = baseA[lev] + (h * W + w) * 3 + a;
            keys[(size_t)b * NTOT + gi] = k;
            boxes[(size_t)b * NTOT + gi] = make_float4(x1, y1, x2, y2);
        }
    }
}

// ---------------------------------------------------------------------------
// Rank-6000 selection: two-level 11-bit histogram refine on the 32-bit key.
// ---------------------------------------------------------------------------
__global__ __launch_bounds__(256) void hist1_k(const u32* __restrict__ keys,
                                               int* __restrict__ hist) {
    __shared__ int hl[2048];
    int img = blockIdx.y, tid = threadIdx.x;
    for (int i = tid; i < 2048; i += 256) hl[i] = 0;
    __syncthreads();
    int gi = blockIdx.x * 256 + tid;
    if (gi < NTOT) atomicAdd(&hl[keys[(size_t)img * NTOT + gi] >> 21], 1);
    __syncthreads();
    for (int i = tid; i < 2048; i += 256)
        if (hl[i]) atomicAdd(&hist[img * 2048 + i], hl[i]);
}

__global__ void scan1_k(const int* __restrict__ hist, int* __restrict__ sel) {
    int img = threadIdx.x;
    if (img >= 2) return;
    int cum = 0, b1 = 2047, C1 = 0;
    for (int b = 0; b < 2048; ++b) {
        int c = hist[img * 2048 + b];
        if (cum + c >= TOPK) { b1 = b; C1 = cum; break; }
        cum += c;
    }
    sel[img * 4 + 0] = b1;
    sel[img * 4 + 1] = C1;
}

__global__ __launch_bounds__(256) void hist2_k(const u32* __restrict__ keys,
                                               const int* __restrict__ sel,
                                               int* __restrict__ hist) {
    __shared__ int hl[2048];
    int img = blockIdx.y, tid = threadIdx.x;
    for (int i = tid; i < 2048; i += 256) hl[i] = 0;
    __syncthreads();
    int b1 = sel[img * 4 + 0];
    int gi = blockIdx.x * 256 + tid;
    if (gi < NTOT) {
        u32 k = keys[(size_t)img * NTOT + gi];
        if ((int)(k >> 21) == b1) atomicAdd(&hl[(k >> 10) & 0x7FF], 1);
    }
    __syncthreads();
    for (int i = tid; i < 2048; i += 256)
        if (hl[i]) atomicAdd(&hist[img * 2048 + i], hl[i]);
}

__global__ void scan2_k(const int* __restrict__ hist2, int* __restrict__ sel) {
    int img = threadIdx.x;
    if (img >= 2) return;
    int b1 = sel[img * 4 + 0];
    int cum = sel[img * 4 + 1];
    int b2 = 2047;
    for (int b = 0; b < 2048; ++b) {
        int c = hist2[img * 2048 + b];
        if (cum + c >= TOPK) { b2 = b; break; }
        cum += c;
    }
    sel[img * 4 + 2] = (b1 << 11) | b2;  // 22-bit prefix threshold
}

__global__ __launch_bounds__(256) void compact_k(const u32* __restrict__ keys,
                                                 const int* __restrict__ sel,
                                                 int* __restrict__ cnt,
                                                 u64* __restrict__ comp) {
    int img = blockIdx.y;
    int gi = blockIdx.x * 256 + threadIdx.x;
    if (gi >= NTOT) return;
    u32 k = keys[(size_t)img * NTOT + gi];
    if ((int)(k >> 10) <= sel[img * 4 + 2]) {
        int slot = atomicAdd(&cnt[img], 1);
        if (slot < COMPCAP)
            comp[(size_t)img * COMPCAP + slot] = ((u64)k << 32) | (u32)gi;
    }
}

// ---------------------------------------------------------------------------
// Bitonic sort of 8192 (key,idx) u64 in LDS; emit top-6000 boxes/areas/valid.
// ---------------------------------------------------------------------------
__global__ __launch_bounds__(1024) void sort_k(const u64* __restrict__ comp,
                                               const float4* __restrict__ boxes,
                                               float4* __restrict__ tb,
                                               float* __restrict__ areas,
                                               int* __restrict__ validA) {
    __shared__ u64 s[COMPCAP];
    int img = blockIdx.x, tid = threadIdx.x;
    for (int i = tid; i < COMPCAP; i += 1024) s[i] = comp[(size_t)img * COMPCAP + i];
    for (int k = 2; k <= COMPCAP; k <<= 1)
        for (int j = k >> 1; j > 0; j >>= 1) {
            __syncthreads();
            for (int t = tid; t < COMPCAP; t += 1024) {
                int l = t ^ j;
                if (l > t) {
                    u64 a = s[t], bb = s[l];
                    bool up = ((t & k) == 0);
                    if ((a > bb) == up) { s[t] = bb; s[l] = a; }
                }
            }
        }
    __syncthreads();
    for (int r = tid; r < TOPK; r += 1024) {
        u64 kv = s[r];
        u32 idx = (u32)(kv & 0xFFFFFFFFull);
        u32 k32 = (u32)(kv >> 32);
        bool valid = (idx < NTOT) && (k32 != INVALID_KEY);
        float4 bx = valid ? boxes[(size_t)img * NTOT + idx] : make_float4(0.f, 0.f, 0.f, 0.f);
        tb[(size_t)img * TOPK + r] = bx;
        areas[(size_t)img * TOPK + r] = valid ? (bx.z - bx.x + 1.f) * (bx.w - bx.y + 1.f) : 0.f;
        validA[(size_t)img * TOPK + r] = valid ? 1 : 0;
    }
}

// ---------------------------------------------------------------------------
// IoU suppression bitmask: mask[i][wj] bit j set iff iou(i, j) > 0.7
// ---------------------------------------------------------------------------
__global__ __launch_bounds__(64) void mask_k(const float4* __restrict__ tb,
                                             const float* __restrict__ areas,
                                             u64* __restrict__ mask) {
    __shared__ float4 jb[64];
    __shared__ float ja[64];
    int img = blockIdx.z, bi = blockIdx.x, bj = blockIdx.y;
    int lane = threadIdx.x;
    int j0 = bj * 64;
    int j = j0 + lane;
    if (j < TOPK) {
        jb[lane] = tb[(size_t)img * TOPK + j];
        ja[lane] = areas[(size_t)img * TOPK + j];
    } else {
        jb[lane] = make_float4(0.f, 0.f, 0.f, 0.f);
        ja[lane] = 0.f;
    }
    __syncthreads();
    int i = bi * 64 + lane;
    if (i >= TOPK) return;
    float4 bb = tb[(size_t)img * TOPK + i];
    float ai = areas[(size_t)img * TOPK + i];
    u64 m = 0;
    int jmax = min(64, TOPK - j0);
    for (int jj = 0; jj < jmax; ++jj) {
        float4 c = jb[jj];
        float ix1 = fmaxf(bb.x, c.x), iy1 = fmaxf(bb.y, c.y);
        float ix2 = fminf(bb.z, c.z), iy2 = fminf(bb.w, c.w);
        float iw = fmaxf(ix2 - ix1 + 1.f, 0.f);
        float ih = fmaxf(iy2 - iy1 + 1.f, 0.f);
        float inter = iw * ih;
        float iou = inter / (ai + ja[jj] - inter);
        if (iou > 0.7f) m |= (1ull << jj);
    }
    mask[(size_t)(img * TOPK + i) * NW + bj] = m;
}

// ---------------------------------------------------------------------------
// Sequential greedy NMS scan (exactly mirrors the reference's fixed-1000-step
// scan). One wave per image; alive bitmask in LDS.
// ---------------------------------------------------------------------------
__global__ __launch_bounds__(64) void nms_scan_k(const float4* __restrict__ tb,
                                                 const int* __restrict__ validA,
                                                 const u64* __restrict__ mask,
                                                 float* __restrict__ out) {
    __shared__ u64 alive[NW];
    int img = blockIdx.x, lane = threadIdx.x;
    for (int wi = lane; wi < NW; wi += 64) {
        u64 w = 0;
        int base = wi * 64;
        for (int t = 0; t < 64; ++t) {
            int j = base + t;
            if (j < TOPK && validA[(size_t)img * TOPK + j]) w |= (1ull << t);
        }
        alive[wi] = w;
    }
    __syncthreads();
    int kept = 0;
    for (int wi = 0; wi < NW && kept < POSTK; ++wi) {
        while (kept < POSTK) {
            u64 w = alive[wi];
            if (!w) break;
            int bit = __builtin_ctzll(w);
            int i = wi * 64 + bit;
            if (lane == 0) {
                float4 bx = tb[(size_t)img * TOPK + i];
                float* o = out + ((size_t)img * POSTK + kept) * 5;
                o[0] = (float)img; o[1] = bx.x; o[2] = bx.y; o[3] = bx.z; o[4] = bx.w;
            }
            ++kept;
            const u64* mrow = mask + (size_t)(img * TOPK + i) * NW;
            u64 m0 = mrow[lane];
            alive[lane] &= ~m0;  // self-iou = 1 > 0.7 clears bit i
            if (lane < NW - 64) {
                u64 m1 = mrow[64 + lane];
                alive[64 + lane] &= ~m1;
            }
            __syncthreads();
        }
    }
}

// ---------------------------------------------------------------------------
extern "C" void kernel_launch(void* const* d_in, const int* in_sizes, int n_in,
                              void* d_out, int out_size, void* d_ws, size_t ws_size,
                              hipStream_t stream) {
    const float* f0 = (const float*)d_in[0];
    const float* f1 = (const float*)d_in[1];
    const float* f2 = (const float*)d_in[2];
    const float* f3 = (const float*)d_in[3];
    const float* f4 = (const float*)d_in[4];
    const float* convw = (const float*)d_in[5];
    const float* convb = (const float*)d_in[6];
    const float* clsw = (const float*)d_in[7];
    const float* clsb = (const float*)d_in[8];
    const float* bbw = (const float*)d_in[9];
    const float* bbb = (const float*)d_in[10];
    const float* iminfo = (const float*)d_in[11];

    char* ws = (char*)d_ws;
    size_t off = 0;
    auto alloc = [&](size_t bytes) -> void* {
        void* p = ws + off;
        off = (off + bytes + 255) & ~(size_t)255;
        return p;
    };
    float* wt = (float*)alloc(589824 * 4);
    u32* keys = (u32*)alloc((size_t)2 * NTOT * 4);
    float4* boxes = (float4*)alloc((size_t)2 * NTOT * 16);
    // contiguous zero region: hist1[2][2048], hist2[2][2048], sel[2][4], cnt[2]
    int* zr = (int*)alloc(2 * 2048 * 4 + 2 * 2048 * 4 + 32 + 8);
    int* hist1 = zr;
    int* hist2 = zr + 2 * 2048;
    int* sel = hist2 + 2 * 2048;
    int* cnt = sel + 8;
    u64* comp = (u64*)alloc((size_t)2 * COMPCAP * 8);
    float4* tb = (float4*)alloc((size_t)2 * TOPK * 16);
    float* areas = (float*)alloc((size_t)2 * TOPK * 4);
    int* validA = (int*)alloc((size_t)2 * TOPK * 4);
    u64* mask = (u64*)alloc((size_t)2 * TOPK * NW * 8);

    hipMemsetAsync(zr, 0, 2 * 2048 * 4 + 2 * 2048 * 4 + 32 + 8, stream);
    hipMemsetAsync(comp, 0xFF, (size_t)2 * COMPCAP * 8, stream);
    hipMemsetAsync(d_out, 0, (size_t)out_size * 4, stream);

    wtrans_k<<<dim3(2304), 256, 0, stream>>>(convw, wt);
    conv_fused_k<<<dim3(2892, 2), 256, 0, stream>>>(f0, f1, f2, f3, f4, wt, convb,
                                                    clsw, clsb, bbw, bbb, iminfo,
                                                    keys, boxes);
    hist1_k<<<dim3(1055, 2), 256, 0, stream>>>(keys, hist1);
    scan1_k<<<1, 64, 0, stream>>>(hist1, sel);
    hist2_k<<<dim3(1055, 2), 256, 0, stream>>>(keys, sel, hist2);
    scan2_k<<<1, 64, 0, stream>>>(hist2, sel);
    compact_k<<<dim3(1055, 2), 256, 0, stream>>>(keys, sel, cnt, comp);
    sort_k<<<2, 1024, 0, stream>>>(comp, boxes, tb, areas, validA);
    mask_k<<<dim3(NW, NW, 2), 64, 0, stream>>>(tb, areas, mask);
    nms_scan_k<<<2, 64, 0, stream>>>(tb, validA, mask, (float*)d_out);
}

// Round 3
// 2911.501 us; speedup vs baseline: 1.5336x; 1.5336x over previous
//
#include <hip/hip_runtime.h>
#include <stdint.h>

typedef unsigned long long u64;
typedef unsigned int u32;
typedef _Float16 f16;
typedef _Float16 half8 __attribute__((ext_vector_type(8)));
typedef float f32x16 __attribute__((ext_vector_type(16)));

#define NTOT 270072
#define TOPK 6000
#define POSTK 1000
#define NW 94              // ceil(6000/64)
#define COMPCAP 8192
#define INVALID_KEY 0xBF800000u

// ---------------------------------------------------------------------------
// Weight transform + fp16x2 split. Input convw OIHW [co][ci][3][3] fp32.
// Output wsp granule layout: [tap][chunk8][co256][cb4][half2][8 f16]
// (tap = kh*3+kw, chunk = ci>>5, cb = (ci>>3)&3). Weights pre-scaled x128 so
// lo-halves stay in fp16 normal range; epilogue divides by 128.
// ---------------------------------------------------------------------------
__global__ __launch_bounds__(256) void wtrans_k(const float* __restrict__ w3,
                                                f16* __restrict__ wsp) {
    int i = blockIdx.x * 256 + threadIdx.x;   // i = co*2304 + ci*9 + tap (coalesced read)
    if (i >= 589824) return;
    float w = w3[i] * 128.0f;
    int tap = i % 9;
    int t2 = i / 9;
    int ci = t2 % 256;
    int co = t2 / 256;
    f16 hi = (f16)w;
    f16 lo = (f16)((w - (float)hi) * 2048.0f);
    int chunk = ci >> 5, cb = (ci >> 3) & 3, j = ci & 7;
    size_t base = ((((size_t)(tap * 8 + chunk) * 256 + co) * 4 + cb) * 2) * 8 + j;
    wsp[base] = hi;        // half 0
    wsp[base + 8] = lo;    // half 1
}

// ---------------------------------------------------------------------------
// MFMA implicit-GEMM conv (fp16x2 split, 3 products) + fused epilogue.
// Block: 512 thr (8 waves), tile M=128 px (4 h-rows x 32 w) x N=256 co.
// Wave (wm = wave>>2, wn = wave&3) owns 64px x 64co = 2x2 tiles of 32x32.
// K-loop: 8 ci-chunks x 9 taps; X halo + W tap-slice staged in LDS (16B
// granules; W uses rotation swizzle (sub+co)&7 to break bank alignment).
// acc_h = Ahi*Whi ; acc_l = Ahi*WloS + AloS*Whi ; out = (acc_h + acc_l/2048)/128.
// ---------------------------------------------------------------------------
__global__ __launch_bounds__(512, 2) void conv_mfma_k(
    const float* __restrict__ f0, const float* __restrict__ f1,
    const float* __restrict__ f2, const float* __restrict__ f3,
    const float* __restrict__ f4,
    const f16* __restrict__ wsp, const float* __restrict__ convb,
    const float* __restrict__ clsw, const float* __restrict__ clsb,
    const float* __restrict__ bbw, const float* __restrict__ bbb,
    const float* __restrict__ im_info,
    u32* __restrict__ keys, float4* __restrict__ boxes)
{
    const int   Ht[5]      = {12, 24, 48, 96, 192};
    const int   Wt[5]      = {22, 44, 88, 176, 352};
    const int   startB[5]  = {0, 3, 15, 51, 195};
    const int   tilesX[5]  = {1, 2, 3, 6, 11};
    const int   baseA[5]   = {0, 792, 3960, 16632, 67320};
    const float scaleA[5]  = {32.f, 16.f, 8.f, 4.f, 2.f};
    const float strideA[5] = {64.f, 32.f, 16.f, 8.f, 4.f};

    __shared__ __align__(16) char lds[62144];
    f16* Xh = (f16*)lds;                         // 6*34*9 granules * 16B = 29376
    float4* Wg4 = (float4*)(lds + 29376);        // 2048 granules * 16B = 32768
    const f16* Whf = (const f16*)(lds + 29376);

    int bid = blockIdx.x;
    int b = blockIdx.y;
    int lev = (bid < 3) ? 0 : (bid < 15) ? 1 : (bid < 51) ? 2 : (bid < 195) ? 3 : 4;
    int t_ = bid - startB[lev];
    int H = Ht[lev], W = Wt[lev];
    int ty = t_ / tilesX[lev];
    int tx = t_ - ty * tilesX[lev];
    int h0 = ty * 4, w0 = tx * 32;
    const float* x = (lev == 0) ? f0 : (lev == 1) ? f1 : (lev == 2) ? f2 : (lev == 3) ? f3 : f4;
    const float* xb = x + (size_t)b * 256 * H * W;

    int tid = threadIdx.x;
    int wave = tid >> 6, lane = tid & 63;
    int wm = wave >> 2, wn = wave & 3;
    int nl = lane & 31, hl = lane >> 5;

    f32x16 acc_h[2][2] = {};
    f32x16 acc_l[2][2] = {};

    for (int chunk = 0; chunk < 8; ++chunk) {
        __syncthreads();                 // previous tap's X readers done
        int ci0 = chunk * 32;
        // stage X halo: 6 rows x 34 cols x 32 ci, fp16 split, granule layout
        for (int i = tid; i < 6528; i += 512) {
            int col = i % 34;
            int r = i / 34;
            int cl = r & 31;
            int row = r >> 5;
            int gh = h0 - 1 + row, gw = w0 - 1 + col;
            float v = 0.f;
            if (gh >= 0 && gh < H && gw >= 0 && gw < W)
                v = xb[(ci0 + cl) * H * W + gh * W + gw];
            f16 hi = (f16)v;
            f16 lo = (f16)((v - (float)hi) * 2048.0f);
            int base = ((row * 34 + col) * 9 + ((cl >> 3) << 1)) * 8 + (cl & 7);
            Xh[base] = hi;
            Xh[base + 8] = lo;
        }
        for (int kh = 0; kh < 3; ++kh)
            for (int kw = 0; kw < 3; ++kw) {
                int tap = kh * 3 + kw;
                __syncthreads();         // prev W readers done (also X-write fence)
                // stage W: 2048 granules of 16B, rotation swizzle on sub-index
                const float4* wsrc = (const float4*)wsp + (size_t)(tap * 8 + chunk) * 2048;
                for (int g = tid; g < 2048; g += 512) {
                    float4 v = wsrc[g];
                    int co = g >> 3, sub = g & 7;
                    Wg4[co * 8 + ((sub + co) & 7)] = v;
                }
                __syncthreads();
#pragma unroll
                for (int s = 0; s < 2; ++s) {
                    half8 ah[2], al[2], bh[2], bl[2];
#pragma unroll
                    for (int mt = 0; mt < 2; ++mt) {
                        int MT = wm * 2 + mt;
                        int gran = ((MT + kh) * 34 + nl + kw) * 9 + (s * 2 + hl) * 2;
                        ah[mt] = *(const half8*)(Xh + gran * 8);
                        al[mt] = *(const half8*)(Xh + gran * 8 + 8);
                    }
#pragma unroll
                    for (int nt = 0; nt < 2; ++nt) {
                        int co = wn * 64 + nt * 32 + nl;
                        int sub = (s * 2 + hl) * 2;
                        bh[nt] = *(const half8*)(Whf + (co * 8 + ((sub + co) & 7)) * 8);
                        bl[nt] = *(const half8*)(Whf + (co * 8 + ((sub + 1 + co) & 7)) * 8);
                    }
#pragma unroll
                    for (int mt = 0; mt < 2; ++mt)
#pragma unroll
                        for (int nt = 0; nt < 2; ++nt) {
                            acc_h[mt][nt] = __builtin_amdgcn_mfma_f32_32x32x16_f16(
                                ah[mt], bh[nt], acc_h[mt][nt], 0, 0, 0);
                            acc_l[mt][nt] = __builtin_amdgcn_mfma_f32_32x32x16_f16(
                                ah[mt], bl[nt], acc_l[mt][nt], 0, 0, 0);
                            acc_l[mt][nt] = __builtin_amdgcn_mfma_f32_32x32x16_f16(
                                al[mt], bh[nt], acc_l[mt][nt], 0, 0, 0);
                        }
                }
            }
    }

    // ---- fused epilogue, one M-row (32 px) at a time ----
    float* tq = (float*)lds;               // 32 x 260 fp32 = 33280 B
    float* arr = (float*)(lds + 33280);    // 32 x 19 fp32 = 2432 B
    const float sc_h = 1.0f / 128.0f;
    const float sc_l = 1.0f / (128.0f * 2048.0f);
    float cb0 = convb[wn * 64 + nl];
    float cb1 = convb[wn * 64 + 32 + nl];

    for (int MT = 0; MT < 4; ++MT) {
        __syncthreads();
        if (wm == (MT >> 1)) {
            int mt = MT & 1;
#pragma unroll
            for (int nt = 0; nt < 2; ++nt) {
                int co = wn * 64 + nt * 32 + nl;
                float bias = nt ? cb1 : cb0;
#pragma unroll
                for (int r = 0; r < 16; ++r) {
                    int p = (r & 3) + 8 * (r >> 2) + 4 * hl;
                    float v = acc_h[mt][nt][r] * sc_h + acc_l[mt][nt][r] * sc_l + bias;
                    tq[p * 260 + co] = fmaxf(v, 0.f);
                }
            }
        }
        __syncthreads();
        // 1x1 convs: 32 px x 18 ch
        float outv[2];
        int nout = 0;
        for (int oi = tid; oi < 576; oi += 512) {
            int px = oi / 18, ch = oi - px * 18;
            const float* wp = (ch < 6) ? (clsw + ch * 256) : (bbw + (ch - 6) * 256);
            float s = (ch < 6) ? clsb[ch] : bbb[ch - 6];
            const float* trow = tq + px * 260;
            for (int co = 0; co < 256; co += 4) {
                float4 wv = *(const float4*)(wp + co);
                float4 tv = *(const float4*)(trow + co);
                s = fmaf(tv.x, wv.x, s);
                s = fmaf(tv.y, wv.y, s);
                s = fmaf(tv.z, wv.z, s);
                s = fmaf(tv.w, wv.w, s);
            }
            outv[nout++] = s;
        }
        {
            int k = 0;
            for (int oi = tid; oi < 576; oi += 512) {
                int px = oi / 18, ch = oi - px * 18;
                arr[px * 19 + ch] = outv[k++];
            }
        }
        __syncthreads();
        // softmax + decode + clip + filter + key for 32 px x 3 anchors
        if (tid < 96) {
            int px = tid / 3, a = tid - px * 3;
            int w = w0 + px;
            int h = h0 + MT;
            if (w < W) {
                const float* e = &arr[px * 19];
                float l0 = e[a * 2], l1 = e[a * 2 + 1];
                float m = fmaxf(l0, l1);
                float e0 = expf(l0 - m), e1 = expf(l1 - m);
                float score = e1 / (e0 + e1);
                float d0 = e[6 + a * 4 + 0], d1 = e[6 + a * 4 + 1];
                float d2 = e[6 + a * 4 + 2], d3 = e[6 + a * 4 + 3];
                const float wsA[3] = {16.f, 11.f, 9.f};
                const float hsA[3] = {16.f, 22.f, 27.f};
                float aw = wsA[a] * scaleA[lev], ah = hsA[a] * scaleA[lev];
                float ax = 8.f + w * strideA[lev];
                float ay = 8.f + h * strideA[lev];
                float pcx = ax + d0 * aw, pcy = ay + d1 * ah;
                float pw = aw * expf(d2), ph = ah * expf(d3);
                float x1 = pcx - 0.5f * pw, y1 = pcy - 0.5f * ph;
                float x2 = pcx + 0.5f * pw, y2 = pcy + 0.5f * ph;
                float him = im_info[b * 6 + 0], wim = im_info[b * 6 + 1], sim = im_info[b * 6 + 2];
                x1 = fminf(fmaxf(x1, 0.f), wim - 1.f);
                y1 = fminf(fmaxf(y1, 0.f), him - 1.f);
                x2 = fminf(fmaxf(x2, 0.f), wim - 1.f);
                y2 = fminf(fmaxf(y2, 0.f), him - 1.f);
                float thr = 2.f * sim;
                float sc = score;
                if (!((x2 - x1 + 1.f >= thr) && (y2 - y1 + 1.f >= thr))) sc = -1.f;
                u32 u = __float_as_uint(sc);
                u32 okey = u ^ ((u >> 31) ? 0xFFFFFFFFu : 0x80000000u);
                u32 k = ~okey;
                int gi = baseA[lev] + (h * W + w) * 3 + a;
                keys[(size_t)b * NTOT + gi] = k;
                boxes[(size_t)b * NTOT + gi] = make_float4(x1, y1, x2, y2);
            }
        }
    }
}

// ---------------------------------------------------------------------------
// Rank-6000 selection: two-level 11-bit histogram refine on the 32-bit key.
// ---------------------------------------------------------------------------
__global__ __launch_bounds__(256) void hist1_k(const u32* __restrict__ keys,
                                               int* __restrict__ hist) {
    __shared__ int hl[2048];
    int img = blockIdx.y, tid = threadIdx.x;
    for (int i = tid; i < 2048; i += 256) hl[i] = 0;
    __syncthreads();
    int gi = blockIdx.x * 256 + tid;
    if (gi < NTOT) atomicAdd(&hl[keys[(size_t)img * NTOT + gi] >> 21], 1);
    __syncthreads();
    for (int i = tid; i < 2048; i += 256)
        if (hl[i]) atomicAdd(&hist[img * 2048 + i], hl[i]);
}

__global__ void scan1_k(const int* __restrict__ hist, int* __restrict__ sel) {
    int img = threadIdx.x;
    if (img >= 2) return;
    int cum = 0, b1 = 2047, C1 = 0;
    for (int b = 0; b < 2048; ++b) {
        int c = hist[img * 2048 + b];
        if (cum + c >= TOPK) { b1 = b; C1 = cum; break; }
        cum += c;
    }
    sel[img * 4 + 0] = b1;
    sel[img * 4 + 1] = C1;
}

__global__ __launch_bounds__(256) void hist2_k(const u32* __restrict__ keys,
                                               const int* __restrict__ sel,
                                               int* __restrict__ hist) {
    __shared__ int hl[2048];
    int img = blockIdx.y, tid = threadIdx.x;
    for (int i = tid; i < 2048; i += 256) hl[i] = 0;
    __syncthreads();
    int b1 = sel[img * 4 + 0];
    int gi = blockIdx.x * 256 + tid;
    if (gi < NTOT) {
        u32 k = keys[(size_t)img * NTOT + gi];
        if ((int)(k >> 21) == b1) atomicAdd(&hl[(k >> 10) & 0x7FF], 1);
    }
    __syncthreads();
    for (int i = tid; i < 2048; i += 256)
        if (hl[i]) atomicAdd(&hist[img * 2048 + i], hl[i]);
}

__global__ void scan2_k(const int* __restrict__ hist2, int* __restrict__ sel) {
    int img = threadIdx.x;
    if (img >= 2) return;
    int b1 = sel[img * 4 + 0];
    int cum = sel[img * 4 + 1];
    int b2 = 2047;
    for (int b = 0; b < 2048; ++b) {
        int c = hist2[img * 2048 + b];
        if (cum + c >= TOPK) { b2 = b; break; }
        cum += c;
    }
    sel[img * 4 + 2] = (b1 << 11) | b2;  // 22-bit prefix threshold
}

__global__ __launch_bounds__(256) void compact_k(const u32* __restrict__ keys,
                                                 const int* __restrict__ sel,
                                                 int* __restrict__ cnt,
                                                 u64* __restrict__ comp) {
    int img = blockIdx.y;
    int gi = blockIdx.x * 256 + threadIdx.x;
    if (gi >= NTOT) return;
    u32 k = keys[(size_t)img * NTOT + gi];
    if ((int)(k >> 10) <= sel[img * 4 + 2]) {
        int slot = atomicAdd(&cnt[img], 1);
        if (slot < COMPCAP)
            comp[(size_t)img * COMPCAP + slot] = ((u64)k << 32) | (u32)gi;
    }
}

// ---------------------------------------------------------------------------
// Bitonic sort of 8192 (key,idx) u64 in LDS; emit top-6000 boxes/areas/valid.
// ---------------------------------------------------------------------------
__global__ __launch_bounds__(1024) void sort_k(const u64* __restrict__ comp,
                                               const float4* __restrict__ boxes,
                                               float4* __restrict__ tb,
                                               float* __restrict__ areas,
                                               int* __restrict__ validA) {
    __shared__ u64 s[COMPCAP];
    int img = blockIdx.x, tid = threadIdx.x;
    for (int i = tid; i < COMPCAP; i += 1024) s[i] = comp[(size_t)img * COMPCAP + i];
    for (int k = 2; k <= COMPCAP; k <<= 1)
        for (int j = k >> 1; j > 0; j >>= 1) {
            __syncthreads();
            for (int t = tid; t < COMPCAP; t += 1024) {
                int l = t ^ j;
                if (l > t) {
                    u64 a = s[t], bb = s[l];
                    bool up = ((t & k) == 0);
                    if ((a > bb) == up) { s[t] = bb; s[l] = a; }
                }
            }
        }
    __syncthreads();
    for (int r = tid; r < TOPK; r += 1024) {
        u64 kv = s[r];
        u32 idx = (u32)(kv & 0xFFFFFFFFull);
        u32 k32 = (u32)(kv >> 32);
        bool valid = (idx < NTOT) && (k32 != INVALID_KEY);
        float4 bx = valid ? boxes[(size_t)img * NTOT + idx] : make_float4(0.f, 0.f, 0.f, 0.f);
        tb[(size_t)img * TOPK + r] = bx;
        areas[(size_t)img * TOPK + r] = valid ? (bx.z - bx.x + 1.f) * (bx.w - bx.y + 1.f) : 0.f;
        validA[(size_t)img * TOPK + r] = valid ? 1 : 0;
    }
}

// ---------------------------------------------------------------------------
// IoU suppression bitmask: mask[i][wj] bit j set iff iou(i, j) > 0.7
// ---------------------------------------------------------------------------
__global__ __launch_bounds__(64) void mask_k(const float4* __restrict__ tb,
                                             const float* __restrict__ areas,
                                             u64* __restrict__ mask) {
    __shared__ float4 jb[64];
    __shared__ float ja[64];
    int img = blockIdx.z, bi = blockIdx.x, bj = blockIdx.y;
    int lane = threadIdx.x;
    int j0 = bj * 64;
    int j = j0 + lane;
    if (j < TOPK) {
        jb[lane] = tb[(size_t)img * TOPK + j];
        ja[lane] = areas[(size_t)img * TOPK + j];
    } else {
        jb[lane] = make_float4(0.f, 0.f, 0.f, 0.f);
        ja[lane] = 0.f;
    }
    __syncthreads();
    int i = bi * 64 + lane;
    if (i >= TOPK) return;
    float4 bb = tb[(size_t)img * TOPK + i];
    float ai = areas[(size_t)img * TOPK + i];
    u64 m = 0;
    int jmax = min(64, TOPK - j0);
    for (int jj = 0; jj < jmax; ++jj) {
        float4 c = jb[jj];
        float ix1 = fmaxf(bb.x, c.x), iy1 = fmaxf(bb.y, c.y);
        float ix2 = fminf(bb.z, c.z), iy2 = fminf(bb.w, c.w);
        float iw = fmaxf(ix2 - ix1 + 1.f, 0.f);
        float ih = fmaxf(iy2 - iy1 + 1.f, 0.f);
        float inter = iw * ih;
        float iou = inter / (ai + ja[jj] - inter);
        if (iou > 0.7f) m |= (1ull << jj);
    }
    mask[(size_t)(img * TOPK + i) * NW + bj] = m;
}

// ---------------------------------------------------------------------------
// Sequential greedy NMS scan (mirrors the reference's fixed-1000-step scan).
// ---------------------------------------------------------------------------
__global__ __launch_bounds__(64) void nms_scan_k(const float4* __restrict__ tb,
                                                 const int* __restrict__ validA,
                                                 const u64* __restrict__ mask,
                                                 float* __restrict__ out) {
    __shared__ u64 alive[NW];
    int img = blockIdx.x, lane = threadIdx.x;
    for (int wi = lane; wi < NW; wi += 64) {
        u64 w = 0;
        int base = wi * 64;
        for (int t = 0; t < 64; ++t) {
            int j = base + t;
            if (j < TOPK && validA[(size_t)img * TOPK + j]) w |= (1ull << t);
        }
        alive[wi] = w;
    }
    __syncthreads();
    int kept = 0;
    for (int wi = 0; wi < NW && kept < POSTK; ++wi) {
        while (kept < POSTK) {
            u64 w = alive[wi];
            if (!w) break;
            int bit = __builtin_ctzll(w);
            int i = wi * 64 + bit;
            if (lane == 0) {
                float4 bx = tb[(size_t)img * TOPK + i];
                float* o = out + ((size_t)img * POSTK + kept) * 5;
                o[0] = (float)img; o[1] = bx.x; o[2] = bx.y; o[3] = bx.z; o[4] = bx.w;
            }
            ++kept;
            const u64* mrow = mask + (size_t)(img * TOPK + i) * NW;
            u64 m0 = mrow[lane];
            alive[lane] &= ~m0;
            if (lane < NW - 64) {
                u64 m1 = mrow[64 + lane];
                alive[64 + lane] &= ~m1;
            }
            __syncthreads();
        }
    }
}

// ---------------------------------------------------------------------------
extern "C" void kernel_launch(void* const* d_in, const int* in_sizes, int n_in,
                              void* d_out, int out_size, void* d_ws, size_t ws_size,
                              hipStream_t stream) {
    const float* f0 = (const float*)d_in[0];
    const float* f1 = (const float*)d_in[1];
    const float* f2 = (const float*)d_in[2];
    const float* f3 = (const float*)d_in[3];
    const float* f4 = (const float*)d_in[4];
    const float* convw = (const float*)d_in[5];
    const float* convb = (const float*)d_in[6];
    const float* clsw = (const float*)d_in[7];
    const float* clsb = (const float*)d_in[8];
    const float* bbw = (const float*)d_in[9];
    const float* bbb = (const float*)d_in[10];
    const float* iminfo = (const float*)d_in[11];

    char* ws = (char*)d_ws;
    size_t off = 0;
    auto alloc = [&](size_t bytes) -> void* {
        void* p = ws + off;
        off = (off + bytes + 255) & ~(size_t)255;
        return p;
    };
    f16* wsp = (f16*)alloc((size_t)1179648 * 2);  // split weights, granule layout
    u32* keys = (u32*)alloc((size_t)2 * NTOT * 4);
    float4* boxes = (float4*)alloc((size_t)2 * NTOT * 16);
    int* zr = (int*)alloc(2 * 2048 * 4 + 2 * 2048 * 4 + 32 + 8);
    int* hist1 = zr;
    int* hist2 = zr + 2 * 2048;
    int* sel = hist2 + 2 * 2048;
    int* cnt = sel + 8;
    u64* comp = (u64*)alloc((size_t)2 * COMPCAP * 8);
    float4* tb = (float4*)alloc((size_t)2 * TOPK * 16);
    float* areas = (float*)alloc((size_t)2 * TOPK * 4);
    int* validA = (int*)alloc((size_t)2 * TOPK * 4);
    u64* mask = (u64*)alloc((size_t)2 * TOPK * NW * 8);

    hipMemsetAsync(zr, 0, 2 * 2048 * 4 + 2 * 2048 * 4 + 32 + 8, stream);
    hipMemsetAsync(comp, 0xFF, (size_t)2 * COMPCAP * 8, stream);
    hipMemsetAsync(d_out, 0, (size_t)out_size * 4, stream);

    wtrans_k<<<dim3(2304), 256, 0, stream>>>(convw, wsp);
    conv_mfma_k<<<dim3(723, 2), 512, 0, stream>>>(f0, f1, f2, f3, f4, wsp, convb,
                                                  clsw, clsb, bbw, bbb, iminfo,
                                                  keys, boxes);
    hist1_k<<<dim3(1055, 2), 256, 0, stream>>>(keys, hist1);
    scan1_k<<<1, 64, 0, stream>>>(hist1, sel);
    hist2_k<<<dim3(1055, 2), 256, 0, stream>>>(keys, sel, hist2);
    scan2_k<<<1, 64, 0, stream>>>(hist2, sel);
    compact_k<<<dim3(1055, 2), 256, 0, stream>>>(keys, sel, cnt, comp);
    sort_k<<<2, 1024, 0, stream>>>(comp, boxes, tb, areas, validA);
    mask_k<<<dim3(NW, NW, 2), 64, 0, stream>>>(tb, areas, mask);
    nms_scan_k<<<2, 64, 0, stream>>>(tb, validA, mask, (float*)d_out);
}